// Round 15
// baseline (265.665 us; speedup 1.0000x reference)
//
#include <hip/hip_runtime.h>
#include <math.h>

typedef short bf16x8 __attribute__((ext_vector_type(8)));
typedef float f32x4  __attribute__((ext_vector_type(4)));

#define N_AG 8192
#define GA   16
#define BLK  512
#define TOB  8
#define TPR  12

// packed bf16 weight regions (offsets in shorts, inside d_ws)
#define PK_ENC 0
#define PK_DEC 98304            // + 6*32*512  (encoder gates)
#define PK_WB  262144           // +10*32*512  (decoder gates)
#define PK_WT  270336           // + 2*8*512   (sW pos-feat rows 128..191)
#define PK_OUT 286720           // + 4*8*512   (sW h rows 0..127)
#define PK_TOT 288768           // + 4*512     (outW 128x5 -> 128x16 frags)

__device__ __forceinline__ unsigned short f2bf(float f) {
    unsigned u = __float_as_uint(f);
    return (unsigned short)((u + 0x7FFFu + ((u >> 16) & 1u)) >> 16);   // RNE
}
__device__ __forceinline__ float bf2f(unsigned short s) {
    return __uint_as_float(((unsigned)s) << 16);
}
__device__ __forceinline__ float v_exp2(float x) {
    float r; asm("v_exp_f32 %0, %1" : "=v"(r) : "v"(x)); return r;
}
__device__ __forceinline__ float v_rcp(float x) {
    float r; asm("v_rcp_f32 %0, %1" : "=v"(r) : "v"(x)); return r;
}
__device__ __forceinline__ unsigned cvtpk(float lo, float hi) {
    unsigned r; asm("v_cvt_pk_bf16_f32 %0, %1, %2" : "=v"(r) : "v"(lo), "v"(hi)); return r;
}
__device__ __forceinline__ float sigm(float x) {
    return v_rcp(1.f + v_exp2(-1.44269504f * x));
}
__device__ __forceinline__ float tanhp(float x) {
    x = fminf(fmaxf(x, -15.f), 15.f);
    float t = v_exp2(2.88539008f * x);             // e^(2x)
    return 1.f - 2.f * v_rcp(t + 1.f);
}

// Pack gate/social/output weights into per-MFMA-fragment bf16 blobs:
// frag(ks,nt) = 64 lanes x 8 shorts; element (l,i) = W[k][col],
// k = ks*32 + (l>>4)*8 + i, col = (nt>>3)*128 + (nt&7)*16 + (l&15)   (gates)
__global__ void pack_w(const float* __restrict__ eWih, const float* __restrict__ eWhh,
                       const float* __restrict__ dWih, const float* __restrict__ dWhh,
                       const float* __restrict__ sW, const float* __restrict__ oW,
                       unsigned short* __restrict__ pk)
{
    for (int idx = blockIdx.x * blockDim.x + threadIdx.x; idx < PK_TOT;
         idx += gridDim.x * blockDim.x) {
        float v;
        if (idx < PK_DEC) {                       // encoder gates: ks 0-1 emb, 2-5 h
            int ks = idx >> 14, rem = idx & 16383;
            int nt = rem >> 9, l = (rem >> 3) & 63, i = rem & 7;
            int klo = ((l >> 4) << 3) + i;
            int col = (nt >> 3) * 128 + (nt & 7) * 16 + (l & 15);
            v = (ks < 2) ? eWih[(ks * 32 + klo) * 512 + col]
                         : eWhh[((ks - 2) * 32 + klo) * 512 + col];
        } else if (idx < PK_WB) {                 // decoder gates: ks 0-1 emb, 2-5 soc, 6-9 h
            int t = idx - PK_DEC;
            int ks = t >> 14, rem = t & 16383;
            int nt = rem >> 9, l = (rem >> 3) & 63, i = rem & 7;
            int klo = ((l >> 4) << 3) + i;
            int col = (nt >> 3) * 128 + (nt & 7) * 16 + (l & 15);
            if (ks < 2)      v = dWih[(ks * 32 + klo) * 512 + col];
            else if (ks < 6) v = dWih[(64 + (ks - 2) * 32 + klo) * 512 + col];
            else             v = dWhh[((ks - 6) * 32 + klo) * 512 + col];
        } else if (idx < PK_WT) {                 // Wb = sW rows 128..191 (pos-feat part), ks<2
            int t = idx - PK_WB;
            int ks = t >> 12, rem = t & 4095;
            int nt = rem >> 9, l = (rem >> 3) & 63, i = rem & 7;
            int klo = ((l >> 4) << 3) + i;
            v = sW[(128 + ks * 32 + klo) * 128 + nt * 16 + (l & 15)];
        } else if (idx < PK_OUT) {                // WT = sW rows 0..127 (h part), ks<4
            int t = idx - PK_WT;
            int ks = t >> 12, rem = t & 4095;
            int nt = rem >> 9, l = (rem >> 3) & 63, i = rem & 7;
            int klo = ((l >> 4) << 3) + i;
            v = sW[(ks * 32 + klo) * 128 + nt * 16 + (l & 15)];
        } else {                                  // outW (128,5) -> 16-col frags, ks<4
            int t = idx - PK_OUT;
            int ks = t >> 9, r = t & 511;
            int l = r >> 3, i = r & 7;
            int klo = ((l >> 4) << 3) + i;
            int col = l & 15;
            v = (col < 5) ? oW[(ks * 32 + klo) * 5 + col] : 0.f;
        }
        pk[idx] = f2bf(v);
    }
}

__global__ __launch_bounds__(BLK, 4)
void slstm(const float* __restrict__ obs, const float* __restrict__ nb_obs,
           const void* __restrict__ nb_mask,
           const float* __restrict__ weW, const float* __restrict__ web,
           const float* __restrict__ eBih, const float* __restrict__ eBhh,
           const float* __restrict__ pW, const float* __restrict__ pb,
           const float* __restrict__ sb,
           const float* __restrict__ wdW, const float* __restrict__ wdb,
           const float* __restrict__ dBih, const float* __restrict__ dBhh,
           const float* __restrict__ outB,
           const unsigned short* __restrict__ pk,
           float* __restrict__ out)
{
    __shared__ __align__(16) float obsrel[TOB][GA][2];
    __shared__ float origin[GA][2];
    __shared__ __align__(16) float rel2[GA][32][2];
    __shared__ unsigned vmaskAll[TOB][GA];
    __shared__ int maskb[GA];
    __shared__ int detf;
    __shared__ __align__(16) short hbf[2][GA * 128];   // bf16 h, XOR-swizzled, ping-pong
    __shared__ __align__(16) short embb[GA * 64];      // bf16 emb, swizzled
    __shared__ __align__(16) short socb[GA * 128];     // bf16 decoder social, swizzled
    __shared__ __align__(16) short pftA[128 * 64];     // 16 KB: pos_feat half-tile (8a x 16nb)
    __shared__ __align__(16) short pftB[128 * 64];     // 16 KB
    __shared__ float cur[GA][2];
    __shared__ __align__(16) float rawb[TPR][GA][5];   // 3.75 KB: deferred raw outputs

    const int j    = threadIdx.x;
    const int lane = j & 63;
    const int w    = j >> 6;          // wave 0..7, owns h-cols [16w, 16w+16)
    const int q    = lane >> 4;
    const int r16  = lane & 15;
    const int swz  = (r16 & 7) << 4;
    const int n0   = blockIdx.x * GA;

    // ---------- init ----------
    if (j < GA) maskb[j] = 0;
    if (j == 0) detf = 0;
    __syncthreads();
    {
        const unsigned* mw = (const unsigned*)nb_mask;
        unsigned w0 = mw[j], w1 = mw[BLK + j];
        int f = 0;
        if (w0 > 1u || w1 > 1u) f |= 1;
        if ((w0 != 0u && w0 != 0x3F800000u) || (w1 != 0u && w1 != 0x3F800000u)) f |= 2;
        if (f) atomicOr(&detf, f);
    }
    __syncthreads();
    const int det = detf;
    const int aT  = j >> 5, i2T = j & 31;            // this thread's (agent, neighbor) slot
    {
        int gi = (n0 + aT) * 32 + i2T;
        int bit;
        if (!(det & 1))      bit = ((const int*)nb_mask)[gi] != 0;
        else if (!(det & 2)) bit = (((const float*)nb_mask)[gi] != 0.f);
        else                 bit = ((const unsigned char*)nb_mask)[gi] != 0;
        if (bit) atomicOr(&maskb[aT], 1 << i2T);
    }
    if (j < 128) {
        int t = j >> 4, a = j & 15;
        float o0 = obs[(n0 + a) * 16 + 14], o1 = obs[(n0 + a) * 16 + 15];
        obsrel[t][a][0] = obs[(n0 + a) * 16 + t * 2]     - o0;
        obsrel[t][a][1] = obs[(n0 + a) * 16 + t * 2 + 1] - o1;
        if (t == 0) { origin[a][0] = o0; origin[a][1] = o1; }
    }
    // neighbor-last position: registerized (thread-fixed (aT,i2T) mapping)
    const float* nbbase = nb_obs + ((size_t)((n0 + aT) * 32 + i2T)) * 16;
    const float nlx = nbbase[14], nly = nbbase[15];
    ((int4*)hbf)[j] = make_int4(0, 0, 0, 0);   // zero both h buffers (8 KB)

    // per-lane constants (slim)
    const int e2 = (j & 31) * 2;                 // pft col pair
    const float pca0 = pW[e2],      pca1 = pW[e2 + 1];
    const float pcc0 = pW[64 + e2], pcc1 = pW[64 + e2 + 1];
    const float pcb0 = pb[e2],      pcb1 = pb[e2 + 1];
    const float ew0 = weW[lane], ew1 = weW[64 + lane], ebv = web[lane];
    const float dw0 = wdW[lane], dw1 = wdW[64 + lane], dbv = wdb[lane];
    const float sbv = sb[w * 16 + r16];
    float bG[4];
    #pragma unroll
    for (int g = 0; g < 4; ++g) {
        int col = g * 128 + w * 16 + r16;
        bG[g] = eBih[col] + eBhh[col];
    }
    const bf16x8* pkE = (const bf16x8*)(pk + PK_ENC);
    const bf16x8* pkD = (const bf16x8*)(pk + PK_DEC);
    const bf16x8* pkB = (const bf16x8*)(pk + PK_WB);
    const bf16x8* pkT = (const bf16x8*)(pk + PK_WT);
    const bf16x8* pkO = (const bf16x8*)(pk + PK_OUT);
    bf16x8 wbf[2];                               // social Wb frags for this wave's 16 cols
    #pragma unroll
    for (int ks = 0; ks < 2; ++ks)
        wbf[ks] = pkB[(ks * 8 + w) * 64 + lane];

    float cst[4];                                // cell state: agent=q*4+rg, col=w*16+r16
    #pragma unroll
    for (int rg = 0; rg < 4; ++rg) cst[rg] = 0.f;

    const f32x4 zz4 = {0.f, 0.f, 0.f, 0.f};
    int pp = 0;
    __syncthreads();

    // ---------- prologue: vmask for ALL steps + rel2[0] + emb[0] ----------
    {
        int mbit = (maskb[aT] >> i2T) & 1;
        #pragma unroll
        for (int t = 0; t < TOB; ++t) {
            float rx = nbbase[2 * t]     - nlx - obsrel[t][aT][0];
            float ry = nbbase[2 * t + 1] - nly - obsrel[t][aT][1];
            bool ok = (rx * rx + ry * ry <= 4.f) && mbit;
            unsigned long long b = __ballot(ok);
            if ((lane & 31) == 0) vmaskAll[t][2 * w + (lane >> 5)] = (unsigned)(b >> (lane & 32));
            if (t == 0) { rel2[aT][i2T][0] = rx; rel2[aT][i2T][1] = ry; }
        }
    }
    {
        float x0 = fmaxf(obsrel[0][w][0] * ew0 + obsrel[0][w][1] * ew1 + ebv, 0.f);
        float x1 = fmaxf(obsrel[0][w + 8][0] * ew0 + obsrel[0][w + 8][1] * ew1 + ebv, 0.f);
        unsigned u = cvtpk(x0, x1);
        char* eb = (char*)embb + w * 128 + ((lane * 2) ^ ((w & 7) << 4));
        *(short*)eb = (short)u;
        *(short*)(eb + 1024) = (short)(u >> 16);
    }
    __syncthreads();

    // fill half-tile c (agents alo..alo+7, neighbors half16..half16+15) into buf
    auto FILL = [&](int c, short* buf) {
        const int half16 = (c >> 1) << 4;
        const int alo = (c & 1) << 3;
        const int rw = j >> 5;                   // il = rw in [0,16)
        unsigned woff = (unsigned)(rw * 128 + ((e2 * 2) ^ ((rw & 7) << 4)));
        const float* rptr = &rel2[alo][half16 + rw][0];
        #pragma unroll
        for (int s = 0; s < 8; ++s) {
            float rx = rptr[0], ry = rptr[1];
            float v0 = fmaxf(fmaf(ry, pcc0, fmaf(rx, pca0, pcb0)), 0.f);
            float v1 = fmaxf(fmaf(ry, pcc1, fmaf(rx, pca1, pcb1)), 0.f);
            *(unsigned*)((char*)buf + woff) = cvtpk(v0, v1);
            woff += 2048;                        // next agent row block (16 rows)
            rptr += 64;                          // next agent (32 nb * 2 floats)
        }
    };
    // social masked-max over half-tile c from buf, folding into ms[0..3]
    auto SOCIAL = [&](int c, const short* buf, float* ms, int t) {
        const int half16 = (c >> 1) << 4;
        const int alo = (c & 1) << 3;
        __builtin_amdgcn_s_setprio(1);
        #pragma unroll 4
        for (int aLoc = 0; aLoc < 8; ++aLoc) {
            int a = alo + aLoc;
            const char* pb2 = (const char*)buf + (aLoc * 16 + r16) * 128;
            bf16x8 af0 = *(const bf16x8*)(pb2 + ((q * 16) ^ swz));
            bf16x8 af1 = *(const bf16x8*)(pb2 + ((64 + q * 16) ^ swz));
            f32x4 ac = __builtin_amdgcn_mfma_f32_16x16x32_bf16(af0, wbf[0], zz4, 0, 0, 0);
            ac = __builtin_amdgcn_mfma_f32_16x16x32_bf16(af1, wbf[1], ac, 0, 0, 0);
            unsigned vbs = vmaskAll[t][a] >> (half16 + q * 4);
            float m0 = ((vbs >> 0) & 1) ? ac[0] : -3e38f;
            float m1 = ((vbs >> 1) & 1) ? ac[1] : -3e38f;
            float m2 = ((vbs >> 2) & 1) ? ac[2] : -3e38f;
            float m3 = ((vbs >> 3) & 1) ? ac[3] : -3e38f;
            float pm = fmaxf(fmaxf(m0, m1), fmaxf(m2, m3));   // tree (max3-fusable)
            pm = fmaxf(pm, __shfl_xor(pm, 16));
            pm = fmaxf(pm, __shfl_xor(pm, 32));
            if (q == (a >> 2)) ms[a & 3] = fmaxf(ms[a & 3], pm);
        }
        __builtin_amdgcn_s_setprio(0);
    };

    // ===================== ENCODER (pipelined phases) =====================
    #pragma unroll 1
    for (int t = 0; t < TOB; ++t) {
        float ms[4];
        #pragma unroll
        for (int rg = 0; rg < 4; ++rg) ms[rg] = -3e38f;
        f32x4 hpA = zz4;
        f32x4 ag[4];
        #pragma unroll
        for (int g = 0; g < 4; ++g) ag[g] = zz4;
        const short* hb = hbf[pp];
        short* hw = hbf[pp ^ 1];

        // ---- p2: fill c0 | hp | gates ----
        FILL(0, pftA);
        __builtin_amdgcn_s_setprio(1);
        #pragma unroll
        for (int ks = 0; ks < 4; ++ks) {
            bf16x8 af = *(const bf16x8*)((const char*)hb + r16 * 256 +
                          (((ks * 32 + q * 8) * 2) ^ swz));
            bf16x8 bfr = pkT[(ks * 8 + w) * 64 + lane];
            hpA = __builtin_amdgcn_mfma_f32_16x16x32_bf16(af, bfr, hpA, 0, 0, 0);
        }
        #pragma unroll 2
        for (int ks = 0; ks < 6; ++ks) {
            bf16x8 af = (ks < 2)
                ? *(const bf16x8*)((const char*)embb + r16 * 128 +
                      (((ks * 32 + q * 8) * 2) ^ swz))
                : *(const bf16x8*)((const char*)hb + r16 * 256 +
                      ((((ks - 2) * 32 + q * 8) * 2) ^ swz));
            #pragma unroll
            for (int g = 0; g < 4; ++g) {
                bf16x8 bfr = pkE[(ks * 32 + g * 8 + w) * 64 + lane];
                ag[g] = __builtin_amdgcn_mfma_f32_16x16x32_bf16(af, bfr, ag[g], 0, 0, 0);
            }
        }
        __builtin_amdgcn_s_setprio(0);
        __syncthreads();

        // ---- p3: fill c1 | social c0 ----
        FILL(1, pftB);
        SOCIAL(0, pftA, ms, t);
        __syncthreads();

        // ---- p4: fill c2 | social c1 ----
        FILL(2, pftA);
        SOCIAL(1, pftB, ms, t);
        __syncthreads();

        // ---- p5: fill c3 | social c2 ----
        FILL(3, pftB);
        SOCIAL(2, pftA, ms, t);
        __syncthreads();

        // ---- p6: social c3 | cell update + h write | rel2/emb for t+1 ----
        SOCIAL(3, pftB, ms, t);
        {
            float hn[4];
            #pragma unroll
            for (int rg = 0; rg < 4; ++rg) {
                float gi = sigm(ag[0][rg] + bG[0]);
                float gf = sigm(ag[1][rg] + bG[1]);
                float gg = tanhp(ag[2][rg] + bG[2]);
                float go = sigm(ag[3][rg] + bG[3]);
                cst[rg] = gf * cst[rg] + gi * gg;
                hn[rg] = go * tanhp(cst[rg]) + 0.3f * fmaxf(ms[rg] + hpA[rg] + sbv, 0.f);
            }
            unsigned u01 = cvtpk(hn[0], hn[1]);
            unsigned u23 = cvtpk(hn[2], hn[3]);
            int hx2 = (w * 16 + r16) * 2;
            *(short*)((char*)hw + (q * 4 + 0) * 256 + (hx2 ^ (((q * 4 + 0) & 7) << 4))) = (short)u01;
            *(short*)((char*)hw + (q * 4 + 1) * 256 + (hx2 ^ (((q * 4 + 1) & 7) << 4))) = (short)(u01 >> 16);
            *(short*)((char*)hw + (q * 4 + 2) * 256 + (hx2 ^ (((q * 4 + 2) & 7) << 4))) = (short)u23;
            *(short*)((char*)hw + (q * 4 + 3) * 256 + (hx2 ^ (((q * 4 + 3) & 7) << 4))) = (short)(u23 >> 16);
        }
        if (t < TOB - 1) {
            const float* base = nbbase + (t + 1) * 2;
            rel2[aT][i2T][0] = base[0] - nlx - obsrel[t + 1][aT][0];
            rel2[aT][i2T][1] = base[1] - nly - obsrel[t + 1][aT][1];
            float x0 = fmaxf(obsrel[t + 1][w][0] * ew0 + obsrel[t + 1][w][1] * ew1 + ebv, 0.f);
            float x1 = fmaxf(obsrel[t + 1][w + 8][0] * ew0 + obsrel[t + 1][w + 8][1] * ew1 + ebv, 0.f);
            unsigned u = cvtpk(x0, x1);
            char* eb = (char*)embb + w * 128 + ((lane * 2) ^ ((w & 7) << 4));
            *(short*)eb = (short)u;
            *(short*)(eb + 1024) = (short)(u >> 16);
        }
        __syncthreads();
        pp ^= 1;
    }

    // ===================== DECODER (3 barriers/step) =====================
    f32x4 hpE = zz4;
    {
        const short* hb = hbf[pp];
        #pragma unroll
        for (int ks = 0; ks < 4; ++ks) {
            bf16x8 af = *(const bf16x8*)((const char*)hb + r16 * 256 +
                          (((ks * 32 + q * 8) * 2) ^ swz));
            bf16x8 bfr = pkT[(ks * 8 + w) * 64 + lane];
            hpE = __builtin_amdgcn_mfma_f32_16x16x32_bf16(af, bfr, hpE, 0, 0, 0);
        }
    }
    #pragma unroll
    for (int g = 0; g < 4; ++g) {
        int col = g * 128 + w * 16 + r16;
        bG[g] = dBih[col] + dBhh[col];
    }
    if (j < 32) cur[j >> 1][j & 1] = 0.f;
    const float obv = outB[r16 < 5 ? r16 : 4];
    __syncthreads();

    #pragma unroll 1
    for (int st = 0; st < TPR; ++st) {
        const short* hb = hbf[pp];
        short* hw = hbf[pp ^ 1];

        // ---- P1 (merged A+B1): emb->LDS | in-reg pos-feat frag | social | socb ----
        {
            float cx0 = cur[w][0], cy0 = cur[w][1];
            float cx1 = cur[w + 8][0], cy1 = cur[w + 8][1];
            float xe0 = fmaxf(cx0 * dw0 + cy0 * dw1 + dbv, 0.f);
            float xe1 = fmaxf(cx1 * dw0 + cy1 * dw1 + dbv, 0.f);
            unsigned ue = cvtpk(xe0, xe1);
            unsigned off = (unsigned)(w * 128 + ((lane * 2) ^ ((w & 7) << 4)));
            *(short*)((char*)embb + off) = (short)ue;
            *(short*)((char*)embb + off + 1024) = (short)(ue >> 16);

            const float cxr = cur[r16][0], cyr = cur[r16][1];
            f32x4 sa = zz4;
            #pragma unroll
            for (int ks = 0; ks < 2; ++ks) {
                const int e0 = ks * 32 + q * 8;
                float4 a0 = *(const float4*)(pW + e0);
                float4 a1 = *(const float4*)(pW + e0 + 4);
                float4 c0 = *(const float4*)(pW + 64 + e0);
                float4 c1 = *(const float4*)(pW + 64 + e0 + 4);
                float4 b0 = *(const float4*)(pb + e0);
                float4 b1 = *(const float4*)(pb + e0 + 4);
                union { unsigned u[4]; bf16x8 v; } pf;
                pf.u[0] = cvtpk(fmaxf(b0.x - cxr * a0.x - cyr * c0.x, 0.f),
                                fmaxf(b0.y - cxr * a0.y - cyr * c0.y, 0.f));
                pf.u[1] = cvtpk(fmaxf(b0.z - cxr * a0.z - cyr * c0.z, 0.f),
                                fmaxf(b0.w - cxr * a0.w - cyr * c0.w, 0.f));
                pf.u[2] = cvtpk(fmaxf(b1.x - cxr * a1.x - cyr * c1.x, 0.f),
                                fmaxf(b1.y - cxr * a1.y - cyr * c1.y, 0.f));
                pf.u[3] = cvtpk(fmaxf(b1.z - cxr * a1.z - cyr * c1.z, 0.f),
                                fmaxf(b1.w - cxr * a1.w - cyr * c1.w, 0.f));
                sa = __builtin_amdgcn_mfma_f32_16x16x32_bf16(pf.v, wbf[ks], sa, 0, 0, 0);
            }
            float sv[4];
            #pragma unroll
            for (int rg = 0; rg < 4; ++rg) {
                int a = q * 4 + rg;
                float cx = cur[a][0], cy = cur[a][1];
                bool vd = (cx * cx + cy * cy <= 4.f) && (maskb[a] != 0);
                float z = sa[rg] + hpE[rg] + sbv;
                sv[rg] = vd ? fmaxf(z, 0.f) : 0.f;
            }
            unsigned u01 = cvtpk(sv[0], sv[1]);
            unsigned u23 = cvtpk(sv[2], sv[3]);
            int hx2 = (w * 16 + r16) * 2;
            *(short*)((char*)socb + (q * 4 + 0) * 256 + (hx2 ^ (((q * 4 + 0) & 7) << 4))) = (short)u01;
            *(short*)((char*)socb + (q * 4 + 1) * 256 + (hx2 ^ (((q * 4 + 1) & 7) << 4))) = (short)(u01 >> 16);
            *(short*)((char*)socb + (q * 4 + 2) * 256 + (hx2 ^ (((q * 4 + 2) & 7) << 4))) = (short)u23;
            *(short*)((char*)socb + (q * 4 + 3) * 256 + (hx2 ^ (((q * 4 + 3) & 7) << 4))) = (short)(u23 >> 16);
        }
        __syncthreads();

        // ---- P2: gates = [emb | soc | h] @ W, ks-outer; cell; h write ----
        f32x4 ag[4];
        #pragma unroll
        for (int g = 0; g < 4; ++g) ag[g] = zz4;
        __builtin_amdgcn_s_setprio(1);
        #pragma unroll 2
        for (int ks = 0; ks < 10; ++ks) {
            bf16x8 af;
            if (ks < 2)
                af = *(const bf16x8*)((const char*)embb + r16 * 128 +
                       (((ks * 32 + q * 8) * 2) ^ swz));
            else if (ks < 6)
                af = *(const bf16x8*)((const char*)socb + r16 * 256 +
                       ((((ks - 2) * 32 + q * 8) * 2) ^ swz));
            else
                af = *(const bf16x8*)((const char*)hb + r16 * 256 +
                       ((((ks - 6) * 32 + q * 8) * 2) ^ swz));
            #pragma unroll
            for (int g = 0; g < 4; ++g) {
                bf16x8 bfr = pkD[(ks * 32 + g * 8 + w) * 64 + lane];
                ag[g] = __builtin_amdgcn_mfma_f32_16x16x32_bf16(af, bfr, ag[g], 0, 0, 0);
            }
        }
        __builtin_amdgcn_s_setprio(0);
        {
            float hn[4];
            #pragma unroll
            for (int rg = 0; rg < 4; ++rg) {
                float gi = sigm(ag[0][rg] + bG[0]);
                float gf = sigm(ag[1][rg] + bG[1]);
                float gg = tanhp(ag[2][rg] + bG[2]);
                float go = sigm(ag[3][rg] + bG[3]);
                cst[rg] = gf * cst[rg] + gi * gg;
                hn[rg] = go * tanhp(cst[rg]);
            }
            unsigned u01 = cvtpk(hn[0], hn[1]);
            unsigned u23 = cvtpk(hn[2], hn[3]);
            int hx2 = (w * 16 + r16) * 2;
            *(short*)((char*)hw + (q * 4 + 0) * 256 + (hx2 ^ (((q * 4 + 0) & 7) << 4))) = (short)u01;
            *(short*)((char*)hw + (q * 4 + 1) * 256 + (hx2 ^ (((q * 4 + 1) & 7) << 4))) = (short)(u01 >> 16);
            *(short*)((char*)hw + (q * 4 + 2) * 256 + (hx2 ^ (((q * 4 + 2) & 7) << 4))) = (short)u23;
            *(short*)((char*)hw + (q * 4 + 3) * 256 + (hx2 ^ (((q * 4 + 3) & 7) << 4))) = (short)(u23 >> 16);
        }
        __syncthreads();
        pp ^= 1;

        // ---- PC: raw = h @ outW via MFMA (wave 0 only); buffer to LDS, feed cur ----
        if (w == 0) {
            const short* hn = hbf[pp];
            f32x4 oc = zz4;
            #pragma unroll
            for (int ks = 0; ks < 4; ++ks) {
                bf16x8 af = *(const bf16x8*)((const char*)hn + r16 * 256 +
                              (((ks * 32 + q * 8) * 2) ^ swz));
                bf16x8 bfr = pkO[ks * 64 + lane];
                oc = __builtin_amdgcn_mfma_f32_16x16x32_bf16(af, bfr, oc, 0, 0, 0);
            }
            if (r16 < 5) {
                #pragma unroll
                for (int rg = 0; rg < 4; ++rg) {
                    int a = q * 4 + rg;
                    float r = oc[rg] + obv;
                    rawb[st][a][r16] = r;
                    if (r16 < 2) cur[a][r16] = r;
                }
            }
        }
        __syncthreads();
    }

    // ---- epilogue: transform + coalesced store of all 960 buffered outputs ----
    #pragma unroll 1
    for (int idx = j; idx < GA * TPR * 5; idx += BLK) {
        int a = idx / (TPR * 5), rem = idx % (TPR * 5);
        int st = rem / 5, p = rem % 5;
        float r = rawb[st][a][p];
        int n = n0 + a;
        if (p < 2) {
            out[n * 24 + st * 2 + p] = r + origin[a][p];
        } else if (p < 4) {
            float cl = fminf(fmaxf(r, -4.f), 4.f);
            out[196608 + n * 24 + st * 2 + (p - 2)] = v_exp2(cl * 1.44269504f);
        } else {
            out[393216 + n * 12 + st] = tanhp(r);
        }
    }
}

extern "C" void kernel_launch(void* const* d_in, const int* in_sizes, int n_in,
                              void* d_out, int out_size, void* d_ws, size_t ws_size,
                              hipStream_t stream) {
    const float* obs    = (const float*)d_in[0];
    const float* nb_obs = (const float*)d_in[1];
    const void*  nb_mask= d_in[2];
    const float* weW    = (const float*)d_in[3];
    const float* web    = (const float*)d_in[4];
    const float* encWih = (const float*)d_in[5];
    const float* encWhh = (const float*)d_in[6];
    const float* encBih = (const float*)d_in[7];
    const float* encBhh = (const float*)d_in[8];
    const float* pW     = (const float*)d_in[9];
    const float* pb     = (const float*)d_in[10];
    const float* sW     = (const float*)d_in[11];
    const float* sbv    = (const float*)d_in[12];
    const float* wdW    = (const float*)d_in[13];
    const float* wdb    = (const float*)d_in[14];
    const float* decWih = (const float*)d_in[15];
    const float* decWhh = (const float*)d_in[16];
    const float* decBih = (const float*)d_in[17];
    const float* decBhh = (const float*)d_in[18];
    const float* outW   = (const float*)d_in[19];
    const float* outB   = (const float*)d_in[20];
    float* out = (float*)d_out;
    unsigned short* pkw = (unsigned short*)d_ws;

    pack_w<<<(PK_TOT + 255) / 256, 256, 0, stream>>>(encWih, encWhh, decWih, decWhh, sW, outW, pkw);
    slstm<<<N_AG / GA, BLK, 0, stream>>>(obs, nb_obs, nb_mask, weW, web,
        encBih, encBhh, pW, pb, sbv, wdW, wdb, decBih, decBhh, outB, pkw, out);
}

// Round 16
// 256.576 us; speedup vs baseline: 1.0354x; 1.0354x over previous
//
#include <hip/hip_runtime.h>
#include <math.h>

typedef short bf16x8 __attribute__((ext_vector_type(8)));
typedef float f32x4  __attribute__((ext_vector_type(4)));

#define N_AG 8192
#define GA   16
#define BLK  512
#define TOB  8
#define TPR  12

// packed bf16 weight regions (offsets in shorts, inside d_ws)
#define PK_ENC 0
#define PK_DEC 98304            // + 6*32*512  (encoder gates)
#define PK_WB  262144           // +10*32*512  (decoder gates)
#define PK_WT  270336           // + 2*8*512   (sW pos-feat rows 128..191)
#define PK_OUT 286720           // + 4*8*512   (sW h rows 0..127)
#define PK_TOT 288768           // + 4*512     (outW 128x5 -> 128x16 frags)

__device__ __forceinline__ unsigned short f2bf(float f) {
    unsigned u = __float_as_uint(f);
    return (unsigned short)((u + 0x7FFFu + ((u >> 16) & 1u)) >> 16);   // RNE
}
__device__ __forceinline__ float bf2f(unsigned short s) {
    return __uint_as_float(((unsigned)s) << 16);
}
__device__ __forceinline__ float v_exp2(float x) {
    float r; asm("v_exp_f32 %0, %1" : "=v"(r) : "v"(x)); return r;
}
__device__ __forceinline__ float v_rcp(float x) {
    float r; asm("v_rcp_f32 %0, %1" : "=v"(r) : "v"(x)); return r;
}
__device__ __forceinline__ unsigned cvtpk(float lo, float hi) {
    unsigned r; asm("v_cvt_pk_bf16_f32 %0, %1, %2" : "=v"(r) : "v"(lo), "v"(hi)); return r;
}
__device__ __forceinline__ float sigm(float x) {
    return v_rcp(1.f + v_exp2(-1.44269504f * x));
}
__device__ __forceinline__ float tanhp(float x) {
    x = fminf(fmaxf(x, -15.f), 15.f);
    float t = v_exp2(2.88539008f * x);             // e^(2x)
    return 1.f - 2.f * v_rcp(t + 1.f);
}

// Pack gate/social/output weights into per-MFMA-fragment bf16 blobs:
// frag(ks,nt) = 64 lanes x 8 shorts; element (l,i) = W[k][col],
// k = ks*32 + (l>>4)*8 + i, col = (nt>>3)*128 + (nt&7)*16 + (l&15)   (gates)
__global__ void pack_w(const float* __restrict__ eWih, const float* __restrict__ eWhh,
                       const float* __restrict__ dWih, const float* __restrict__ dWhh,
                       const float* __restrict__ sW, const float* __restrict__ oW,
                       unsigned short* __restrict__ pk)
{
    for (int idx = blockIdx.x * blockDim.x + threadIdx.x; idx < PK_TOT;
         idx += gridDim.x * blockDim.x) {
        float v;
        if (idx < PK_DEC) {                       // encoder gates: ks 0-1 emb, 2-5 h
            int ks = idx >> 14, rem = idx & 16383;
            int nt = rem >> 9, l = (rem >> 3) & 63, i = rem & 7;
            int klo = ((l >> 4) << 3) + i;
            int col = (nt >> 3) * 128 + (nt & 7) * 16 + (l & 15);
            v = (ks < 2) ? eWih[(ks * 32 + klo) * 512 + col]
                         : eWhh[((ks - 2) * 32 + klo) * 512 + col];
        } else if (idx < PK_WB) {                 // decoder gates: ks 0-1 emb, 2-5 soc, 6-9 h
            int t = idx - PK_DEC;
            int ks = t >> 14, rem = t & 16383;
            int nt = rem >> 9, l = (rem >> 3) & 63, i = rem & 7;
            int klo = ((l >> 4) << 3) + i;
            int col = (nt >> 3) * 128 + (nt & 7) * 16 + (l & 15);
            if (ks < 2)      v = dWih[(ks * 32 + klo) * 512 + col];
            else if (ks < 6) v = dWih[(64 + (ks - 2) * 32 + klo) * 512 + col];
            else             v = dWhh[((ks - 6) * 32 + klo) * 512 + col];
        } else if (idx < PK_WT) {                 // Wb = sW rows 128..191 (pos-feat part), ks<2
            int t = idx - PK_WB;
            int ks = t >> 12, rem = t & 4095;
            int nt = rem >> 9, l = (rem >> 3) & 63, i = rem & 7;
            int klo = ((l >> 4) << 3) + i;
            v = sW[(128 + ks * 32 + klo) * 128 + nt * 16 + (l & 15)];
        } else if (idx < PK_OUT) {                // WT = sW rows 0..127 (h part), ks<4
            int t = idx - PK_WT;
            int ks = t >> 12, rem = t & 4095;
            int nt = rem >> 9, l = (rem >> 3) & 63, i = rem & 7;
            int klo = ((l >> 4) << 3) + i;
            v = sW[(ks * 32 + klo) * 128 + nt * 16 + (l & 15)];
        } else {                                  // outW (128,5) -> 16-col frags, ks<4
            int t = idx - PK_OUT;
            int ks = t >> 9, r = t & 511;
            int l = r >> 3, i = r & 7;
            int klo = ((l >> 4) << 3) + i;
            int col = l & 15;
            v = (col < 5) ? oW[(ks * 32 + klo) * 5 + col] : 0.f;
        }
        pk[idx] = f2bf(v);
    }
}

__global__ __launch_bounds__(BLK, 4)
void slstm(const float* __restrict__ obs, const float* __restrict__ nb_obs,
           const void* __restrict__ nb_mask,
           const float* __restrict__ weW, const float* __restrict__ web,
           const float* __restrict__ eBih, const float* __restrict__ eBhh,
           const float* __restrict__ pW, const float* __restrict__ pb,
           const float* __restrict__ sb,
           const float* __restrict__ wdW, const float* __restrict__ wdb,
           const float* __restrict__ dBih, const float* __restrict__ dBhh,
           const float* __restrict__ outB,
           const unsigned short* __restrict__ pk,
           float* __restrict__ out)
{
    __shared__ __align__(16) float obsrel[TOB][GA][2];
    __shared__ float origin[GA][2];
    __shared__ __align__(16) float nblast[GA][32][2];
    __shared__ __align__(16) float rel2[GA][32][2];
    __shared__ unsigned vmaskAll[TOB][GA];
    __shared__ int maskb[GA];
    __shared__ int detf;
    __shared__ __align__(16) short hbf[2][GA * 128];   // bf16 h, XOR-swizzled, ping-pong
    __shared__ __align__(16) short embb[GA * 64];      // bf16 emb, swizzled
    __shared__ __align__(16) short socb[GA * 128];     // bf16 decoder social, swizzled
    __shared__ __align__(16) short pfdb[GA * 64];      // bf16 decoder pos_feat, swizzled
    __shared__ __align__(16) short pftA[128 * 64];     // 16 KB: pos_feat half-tile (8a x 16nb)
    __shared__ __align__(16) short pftB[128 * 64];     // 16 KB
    __shared__ float cur[GA][2];
    __shared__ __align__(16) float rawb[TPR][GA][5];   // 3.75 KB: deferred raw outputs

    const int j    = threadIdx.x;
    const int lane = j & 63;
    const int w    = j >> 6;          // wave 0..7, owns h-cols [16w, 16w+16)
    const int q    = lane >> 4;
    const int r16  = lane & 15;
    const int swz  = (r16 & 7) << 4;
    const int n0   = blockIdx.x * GA;

    // ---------- init ----------
    if (j < GA) maskb[j] = 0;
    if (j == 0) detf = 0;
    __syncthreads();
    {
        const unsigned* mw = (const unsigned*)nb_mask;
        unsigned w0 = mw[j], w1 = mw[BLK + j];
        int f = 0;
        if (w0 > 1u || w1 > 1u) f |= 1;
        if ((w0 != 0u && w0 != 0x3F800000u) || (w1 != 0u && w1 != 0x3F800000u)) f |= 2;
        if (f) atomicOr(&detf, f);
    }
    __syncthreads();
    const int det = detf;
    {
        int a = j >> 5, i2 = j & 31, gi = (n0 + a) * 32 + i2;
        int bit;
        if (!(det & 1))      bit = ((const int*)nb_mask)[gi] != 0;
        else if (!(det & 2)) bit = (((const float*)nb_mask)[gi] != 0.f);
        else                 bit = ((const unsigned char*)nb_mask)[gi] != 0;
        if (bit) atomicOr(&maskb[a], 1 << i2);
    }
    if (j < 128) {
        int t = j >> 4, a = j & 15;
        float o0 = obs[(n0 + a) * 16 + 14], o1 = obs[(n0 + a) * 16 + 15];
        obsrel[t][a][0] = obs[(n0 + a) * 16 + t * 2]     - o0;
        obsrel[t][a][1] = obs[(n0 + a) * 16 + t * 2 + 1] - o1;
        if (t == 0) { origin[a][0] = o0; origin[a][1] = o1; }
    }
    {
        int a = j >> 5, i2 = j & 31;
        const float* nb = nb_obs + ((size_t)((n0 + a) * 32 + i2)) * 16 + 14;
        nblast[a][i2][0] = nb[0];
        nblast[a][i2][1] = nb[1];
    }
    ((int4*)hbf)[j] = make_int4(0, 0, 0, 0);   // zero both h buffers (8 KB)

    // per-lane constants (slim)
    const int e2 = (j & 31) * 2;                 // pft col pair
    const float pca0 = pW[e2],      pca1 = pW[e2 + 1];
    const float pcc0 = pW[64 + e2], pcc1 = pW[64 + e2 + 1];
    const float pcb0 = pb[e2],      pcb1 = pb[e2 + 1];
    const float ew0 = weW[lane], ew1 = weW[64 + lane], ebv = web[lane];
    const float dw0 = wdW[lane], dw1 = wdW[64 + lane], dbv = wdb[lane];
    const float pwa = pW[lane], pwc = pW[64 + lane], pbb = pb[lane];
    const float sbv = sb[w * 16 + r16];
    float bG[4];
    #pragma unroll
    for (int g = 0; g < 4; ++g) {
        int col = g * 128 + w * 16 + r16;
        bG[g] = eBih[col] + eBhh[col];
    }
    const bf16x8* pkE = (const bf16x8*)(pk + PK_ENC);
    const bf16x8* pkD = (const bf16x8*)(pk + PK_DEC);
    const bf16x8* pkB = (const bf16x8*)(pk + PK_WB);
    const bf16x8* pkT = (const bf16x8*)(pk + PK_WT);
    const bf16x8* pkO = (const bf16x8*)(pk + PK_OUT);
    bf16x8 wbf[2];                               // social Wb frags for this wave's 16 cols
    #pragma unroll
    for (int ks = 0; ks < 2; ++ks)
        wbf[ks] = pkB[(ks * 8 + w) * 64 + lane];

    float cst[4];                                // cell state: agent=q*4+rg, col=w*16+r16
    #pragma unroll
    for (int rg = 0; rg < 4; ++rg) cst[rg] = 0.f;

    const f32x4 zz4 = {0.f, 0.f, 0.f, 0.f};
    int pp = 0;
    __syncthreads();

    // ---------- prologue: vmask for ALL steps + rel2[0] + emb[0] ----------
    {
        int a = j >> 5, i2 = j & 31;
        const float* base = nb_obs + ((size_t)((n0 + a) * 32 + i2)) * 16;
        float nlx = nblast[a][i2][0], nly = nblast[a][i2][1];
        int mbit = (maskb[a] >> i2) & 1;
        #pragma unroll
        for (int t = 0; t < TOB; ++t) {
            float rx = base[2 * t]     - nlx - obsrel[t][a][0];
            float ry = base[2 * t + 1] - nly - obsrel[t][a][1];
            bool ok = (rx * rx + ry * ry <= 4.f) && mbit;
            unsigned long long b = __ballot(ok);
            if ((lane & 31) == 0) vmaskAll[t][2 * w + (lane >> 5)] = (unsigned)(b >> (lane & 32));
            if (t == 0) { rel2[a][i2][0] = rx; rel2[a][i2][1] = ry; }
        }
    }
    {
        float x0 = fmaxf(obsrel[0][w][0] * ew0 + obsrel[0][w][1] * ew1 + ebv, 0.f);
        float x1 = fmaxf(obsrel[0][w + 8][0] * ew0 + obsrel[0][w + 8][1] * ew1 + ebv, 0.f);
        unsigned u = cvtpk(x0, x1);
        char* eb = (char*)embb + w * 128 + ((lane * 2) ^ ((w & 7) << 4));
        *(short*)eb = (short)u;
        *(short*)(eb + 1024) = (short)(u >> 16);
    }
    __syncthreads();

    // fill half-tile c (agents alo..alo+7, neighbors half16..half16+15) into buf
    auto FILL = [&](int c, short* buf) {
        const int half16 = (c >> 1) << 4;
        const int alo = (c & 1) << 3;
        const int rw = j >> 5;                   // il = rw in [0,16)
        unsigned woff = (unsigned)(rw * 128 + ((e2 * 2) ^ ((rw & 7) << 4)));
        const float* rptr = &rel2[alo][half16 + rw][0];
        #pragma unroll
        for (int s = 0; s < 8; ++s) {
            float rx = rptr[0], ry = rptr[1];
            float v0 = fmaxf(fmaf(ry, pcc0, fmaf(rx, pca0, pcb0)), 0.f);
            float v1 = fmaxf(fmaf(ry, pcc1, fmaf(rx, pca1, pcb1)), 0.f);
            *(unsigned*)((char*)buf + woff) = cvtpk(v0, v1);
            woff += 2048;                        // next agent row block (16 rows)
            rptr += 64;                          // next agent (32 nb * 2 floats)
        }
    };
    // social masked-max over half-tile c from buf, folding into ms[0..3]
    auto SOCIAL = [&](int c, const short* buf, float* ms, int t) {
        const int half16 = (c >> 1) << 4;
        const int alo = (c & 1) << 3;
        __builtin_amdgcn_s_setprio(1);
        #pragma unroll 4
        for (int aLoc = 0; aLoc < 8; ++aLoc) {
            int a = alo + aLoc;
            const char* pb2 = (const char*)buf + (aLoc * 16 + r16) * 128;
            bf16x8 af0 = *(const bf16x8*)(pb2 + ((q * 16) ^ swz));
            bf16x8 af1 = *(const bf16x8*)(pb2 + ((64 + q * 16) ^ swz));
            f32x4 ac = __builtin_amdgcn_mfma_f32_16x16x32_bf16(af0, wbf[0], zz4, 0, 0, 0);
            ac = __builtin_amdgcn_mfma_f32_16x16x32_bf16(af1, wbf[1], ac, 0, 0, 0);
            unsigned vbs = vmaskAll[t][a] >> (half16 + q * 4);
            float pm = ((vbs >> 0) & 1) ? ac[0] : -3e38f;
            pm = fmaxf(pm, ((vbs >> 1) & 1) ? ac[1] : -3e38f);
            pm = fmaxf(pm, ((vbs >> 2) & 1) ? ac[2] : -3e38f);
            pm = fmaxf(pm, ((vbs >> 3) & 1) ? ac[3] : -3e38f);
            pm = fmaxf(pm, __shfl_xor(pm, 16));
            pm = fmaxf(pm, __shfl_xor(pm, 32));
            if (q == (a >> 2)) ms[a & 3] = fmaxf(ms[a & 3], pm);
        }
        __builtin_amdgcn_s_setprio(0);
    };

    // ===================== ENCODER (pipelined phases) =====================
    #pragma unroll 1
    for (int t = 0; t < TOB; ++t) {
        float ms[4];
        #pragma unroll
        for (int rg = 0; rg < 4; ++rg) ms[rg] = -3e38f;
        f32x4 hpA = zz4;
        f32x4 ag[4];
        #pragma unroll
        for (int g = 0; g < 4; ++g) ag[g] = zz4;
        const short* hb = hbf[pp];
        short* hw = hbf[pp ^ 1];

        // ---- p2: fill c0 | hp | gates ----
        FILL(0, pftA);
        __builtin_amdgcn_s_setprio(1);
        #pragma unroll
        for (int ks = 0; ks < 4; ++ks) {
            bf16x8 af = *(const bf16x8*)((const char*)hb + r16 * 256 +
                          (((ks * 32 + q * 8) * 2) ^ swz));
            bf16x8 bfr = pkT[(ks * 8 + w) * 64 + lane];
            hpA = __builtin_amdgcn_mfma_f32_16x16x32_bf16(af, bfr, hpA, 0, 0, 0);
        }
        #pragma unroll 2
        for (int ks = 0; ks < 6; ++ks) {
            bf16x8 af = (ks < 2)
                ? *(const bf16x8*)((const char*)embb + r16 * 128 +
                      (((ks * 32 + q * 8) * 2) ^ swz))
                : *(const bf16x8*)((const char*)hb + r16 * 256 +
                      ((((ks - 2) * 32 + q * 8) * 2) ^ swz));
            #pragma unroll
            for (int g = 0; g < 4; ++g) {
                bf16x8 bfr = pkE[(ks * 32 + g * 8 + w) * 64 + lane];
                ag[g] = __builtin_amdgcn_mfma_f32_16x16x32_bf16(af, bfr, ag[g], 0, 0, 0);
            }
        }
        __builtin_amdgcn_s_setprio(0);
        __syncthreads();

        // ---- p3: fill c1 | social c0 ----
        FILL(1, pftB);
        SOCIAL(0, pftA, ms, t);
        __syncthreads();

        // ---- p4: fill c2 | social c1 ----
        FILL(2, pftA);
        SOCIAL(1, pftB, ms, t);
        __syncthreads();

        // ---- p5: fill c3 | social c2 ----
        FILL(3, pftB);
        SOCIAL(2, pftA, ms, t);
        __syncthreads();

        // ---- p6: social c3 | cell update + h write | rel2/emb for t+1 ----
        SOCIAL(3, pftB, ms, t);
        {
            float hn[4];
            #pragma unroll
            for (int rg = 0; rg < 4; ++rg) {
                float gi = sigm(ag[0][rg] + bG[0]);
                float gf = sigm(ag[1][rg] + bG[1]);
                float gg = tanhp(ag[2][rg] + bG[2]);
                float go = sigm(ag[3][rg] + bG[3]);
                cst[rg] = gf * cst[rg] + gi * gg;
                hn[rg] = go * tanhp(cst[rg]) + 0.3f * fmaxf(ms[rg] + hpA[rg] + sbv, 0.f);
            }
            unsigned u01 = cvtpk(hn[0], hn[1]);
            unsigned u23 = cvtpk(hn[2], hn[3]);
            int hx2 = (w * 16 + r16) * 2;
            *(short*)((char*)hw + (q * 4 + 0) * 256 + (hx2 ^ (((q * 4 + 0) & 7) << 4))) = (short)u01;
            *(short*)((char*)hw + (q * 4 + 1) * 256 + (hx2 ^ (((q * 4 + 1) & 7) << 4))) = (short)(u01 >> 16);
            *(short*)((char*)hw + (q * 4 + 2) * 256 + (hx2 ^ (((q * 4 + 2) & 7) << 4))) = (short)u23;
            *(short*)((char*)hw + (q * 4 + 3) * 256 + (hx2 ^ (((q * 4 + 3) & 7) << 4))) = (short)(u23 >> 16);
        }
        if (t < TOB - 1) {
            int a = j >> 5, i2 = j & 31;
            const float* base = nb_obs + ((size_t)((n0 + a) * 32 + i2)) * 16 + (t + 1) * 2;
            rel2[a][i2][0] = base[0] - nblast[a][i2][0] - obsrel[t + 1][a][0];
            rel2[a][i2][1] = base[1] - nblast[a][i2][1] - obsrel[t + 1][a][1];
            float x0 = fmaxf(obsrel[t + 1][w][0] * ew0 + obsrel[t + 1][w][1] * ew1 + ebv, 0.f);
            float x1 = fmaxf(obsrel[t + 1][w + 8][0] * ew0 + obsrel[t + 1][w + 8][1] * ew1 + ebv, 0.f);
            unsigned u = cvtpk(x0, x1);
            char* eb = (char*)embb + w * 128 + ((lane * 2) ^ ((w & 7) << 4));
            *(short*)eb = (short)u;
            *(short*)(eb + 1024) = (short)(u >> 16);
        }
        __syncthreads();
        pp ^= 1;
    }

    // ===================== DECODER =====================
    f32x4 hpE = zz4;
    {
        const short* hb = hbf[pp];
        #pragma unroll
        for (int ks = 0; ks < 4; ++ks) {
            bf16x8 af = *(const bf16x8*)((const char*)hb + r16 * 256 +
                          (((ks * 32 + q * 8) * 2) ^ swz));
            bf16x8 bfr = pkT[(ks * 8 + w) * 64 + lane];
            hpE = __builtin_amdgcn_mfma_f32_16x16x32_bf16(af, bfr, hpE, 0, 0, 0);
        }
    }
    #pragma unroll
    for (int g = 0; g < 4; ++g) {
        int col = g * 128 + w * 16 + r16;
        bG[g] = dBih[col] + dBhh[col];
    }
    if (j < 32) cur[j >> 1][j & 1] = 0.f;
    const float obv = outB[r16 < 5 ? r16 : 4];
    __syncthreads();

    #pragma unroll 1
    for (int st = 0; st < TPR; ++st) {
        // ---- A: emb(cur) + pos_feat(-cur), packed ----
        {
            float cx0 = cur[w][0], cy0 = cur[w][1];
            float cx1 = cur[w + 8][0], cy1 = cur[w + 8][1];
            float xe0 = fmaxf(cx0 * dw0 + cy0 * dw1 + dbv, 0.f);
            float xe1 = fmaxf(cx1 * dw0 + cy1 * dw1 + dbv, 0.f);
            float vp0 = fmaxf(pbb - cx0 * pwa - cy0 * pwc, 0.f);
            float vp1 = fmaxf(pbb - cx1 * pwa - cy1 * pwc, 0.f);
            unsigned ue = cvtpk(xe0, xe1);
            unsigned up = cvtpk(vp0, vp1);
            unsigned off = (unsigned)(w * 128 + ((lane * 2) ^ ((w & 7) << 4)));
            *(short*)((char*)embb + off) = (short)ue;
            *(short*)((char*)embb + off + 1024) = (short)(ue >> 16);
            *(short*)((char*)pfdb + off) = (short)up;
            *(short*)((char*)pfdb + off + 1024) = (short)(up >> 16);
        }
        __syncthreads();

        // ---- B1: social (single M-tile of 16 agents) ----
        const short* hb = hbf[pp];
        short* hw = hbf[pp ^ 1];
        {
            f32x4 sa = zz4;
            #pragma unroll
            for (int ks = 0; ks < 2; ++ks) {
                bf16x8 af = *(const bf16x8*)((const char*)pfdb + r16 * 128 +
                              (((ks * 32 + q * 8) * 2) ^ swz));
                sa = __builtin_amdgcn_mfma_f32_16x16x32_bf16(af, wbf[ks], sa, 0, 0, 0);
            }
            float sv[4];
            #pragma unroll
            for (int rg = 0; rg < 4; ++rg) {
                int a = q * 4 + rg;
                float cx = cur[a][0], cy = cur[a][1];
                bool vd = (cx * cx + cy * cy <= 4.f) && (maskb[a] != 0);
                float z = sa[rg] + hpE[rg] + sbv;
                sv[rg] = vd ? fmaxf(z, 0.f) : 0.f;
            }
            unsigned u01 = cvtpk(sv[0], sv[1]);
            unsigned u23 = cvtpk(sv[2], sv[3]);
            int hx2 = (w * 16 + r16) * 2;
            *(short*)((char*)socb + (q * 4 + 0) * 256 + (hx2 ^ (((q * 4 + 0) & 7) << 4))) = (short)u01;
            *(short*)((char*)socb + (q * 4 + 1) * 256 + (hx2 ^ (((q * 4 + 1) & 7) << 4))) = (short)(u01 >> 16);
            *(short*)((char*)socb + (q * 4 + 2) * 256 + (hx2 ^ (((q * 4 + 2) & 7) << 4))) = (short)u23;
            *(short*)((char*)socb + (q * 4 + 3) * 256 + (hx2 ^ (((q * 4 + 3) & 7) << 4))) = (short)(u23 >> 16);
        }
        __syncthreads();

        // ---- B2: gates = [emb | soc | h] @ W, ks-outer ----
        f32x4 ag[4];
        #pragma unroll
        for (int g = 0; g < 4; ++g) ag[g] = zz4;
        __builtin_amdgcn_s_setprio(1);
        #pragma unroll 2
        for (int ks = 0; ks < 10; ++ks) {
            bf16x8 af;
            if (ks < 2)
                af = *(const bf16x8*)((const char*)embb + r16 * 128 +
                       (((ks * 32 + q * 8) * 2) ^ swz));
            else if (ks < 6)
                af = *(const bf16x8*)((const char*)socb + r16 * 256 +
                       ((((ks - 2) * 32 + q * 8) * 2) ^ swz));
            else
                af = *(const bf16x8*)((const char*)hb + r16 * 256 +
                       ((((ks - 6) * 32 + q * 8) * 2) ^ swz));
            #pragma unroll
            for (int g = 0; g < 4; ++g) {
                bf16x8 bfr = pkD[(ks * 32 + g * 8 + w) * 64 + lane];
                ag[g] = __builtin_amdgcn_mfma_f32_16x16x32_bf16(af, bfr, ag[g], 0, 0, 0);
            }
        }
        __builtin_amdgcn_s_setprio(0);
        {
            float hn[4];
            #pragma unroll
            for (int rg = 0; rg < 4; ++rg) {
                float gi = sigm(ag[0][rg] + bG[0]);
                float gf = sigm(ag[1][rg] + bG[1]);
                float gg = tanhp(ag[2][rg] + bG[2]);
                float go = sigm(ag[3][rg] + bG[3]);
                cst[rg] = gf * cst[rg] + gi * gg;
                hn[rg] = go * tanhp(cst[rg]);
            }
            unsigned u01 = cvtpk(hn[0], hn[1]);
            unsigned u23 = cvtpk(hn[2], hn[3]);
            int hx2 = (w * 16 + r16) * 2;
            *(short*)((char*)hw + (q * 4 + 0) * 256 + (hx2 ^ (((q * 4 + 0) & 7) << 4))) = (short)u01;
            *(short*)((char*)hw + (q * 4 + 1) * 256 + (hx2 ^ (((q * 4 + 1) & 7) << 4))) = (short)(u01 >> 16);
            *(short*)((char*)hw + (q * 4 + 2) * 256 + (hx2 ^ (((q * 4 + 2) & 7) << 4))) = (short)u23;
            *(short*)((char*)hw + (q * 4 + 3) * 256 + (hx2 ^ (((q * 4 + 3) & 7) << 4))) = (short)(u23 >> 16);
        }
        __syncthreads();
        pp ^= 1;

        // ---- PC: raw = h @ outW via MFMA (wave 0 only); buffer to LDS, feed cur ----
        if (w == 0) {
            const short* hn = hbf[pp];
            f32x4 oc = zz4;
            #pragma unroll
            for (int ks = 0; ks < 4; ++ks) {
                bf16x8 af = *(const bf16x8*)((const char*)hn + r16 * 256 +
                              (((ks * 32 + q * 8) * 2) ^ swz));
                bf16x8 bfr = pkO[ks * 64 + lane];
                oc = __builtin_amdgcn_mfma_f32_16x16x32_bf16(af, bfr, oc, 0, 0, 0);
            }
            if (r16 < 5) {
                #pragma unroll
                for (int rg = 0; rg < 4; ++rg) {
                    int a = q * 4 + rg;
                    float r = oc[rg] + obv;
                    rawb[st][a][r16] = r;
                    if (r16 < 2) cur[a][r16] = r;
                }
            }
        }
        __syncthreads();
    }

    // ---- epilogue: transform + coalesced store of all 960 buffered outputs ----
    #pragma unroll 1
    for (int idx = j; idx < GA * TPR * 5; idx += BLK) {
        int a = idx / (TPR * 5), rem = idx % (TPR * 5);
        int st = rem / 5, p = rem % 5;
        float r = rawb[st][a][p];
        int n = n0 + a;
        if (p < 2) {
            out[n * 24 + st * 2 + p] = r + origin[a][p];
        } else if (p < 4) {
            float cl = fminf(fmaxf(r, -4.f), 4.f);
            out[196608 + n * 24 + st * 2 + (p - 2)] = v_exp2(cl * 1.44269504f);
        } else {
            out[393216 + n * 12 + st] = tanhp(r);
        }
    }
}

extern "C" void kernel_launch(void* const* d_in, const int* in_sizes, int n_in,
                              void* d_out, int out_size, void* d_ws, size_t ws_size,
                              hipStream_t stream) {
    const float* obs    = (const float*)d_in[0];
    const float* nb_obs = (const float*)d_in[1];
    const void*  nb_mask= d_in[2];
    const float* weW    = (const float*)d_in[3];
    const float* web    = (const float*)d_in[4];
    const float* encWih = (const float*)d_in[5];
    const float* encWhh = (const float*)d_in[6];
    const float* encBih = (const float*)d_in[7];
    const float* encBhh = (const float*)d_in[8];
    const float* pW     = (const float*)d_in[9];
    const float* pb     = (const float*)d_in[10];
    const float* sW     = (const float*)d_in[11];
    const float* sbv    = (const float*)d_in[12];
    const float* wdW    = (const float*)d_in[13];
    const float* wdb    = (const float*)d_in[14];
    const float* decWih = (const float*)d_in[15];
    const float* decWhh = (const float*)d_in[16];
    const float* decBih = (const float*)d_in[17];
    const float* decBhh = (const float*)d_in[18];
    const float* outW   = (const float*)d_in[19];
    const float* outB   = (const float*)d_in[20];
    float* out = (float*)d_out;
    unsigned short* pkw = (unsigned short*)d_ws;

    pack_w<<<(PK_TOT + 255) / 256, 256, 0, stream>>>(encWih, encWhh, decWih, decWhh, sW, outW, pkw);
    slstm<<<N_AG / GA, BLK, 0, stream>>>(obs, nb_obs, nb_mask, weW, web,
        encBih, encBhh, pW, pb, sbv, wdW, wdb, decBih, decBhh, outB, pkw, out);
}